// Round 1
// 1111.608 us; speedup vs baseline: 1.4925x; 1.4925x over previous
//
#include <hip/hip_runtime.h>
#include <hip/hip_bf16.h>

#define TT 2048   // tokens
#define HH 2048   // hidden
#define EE 32     // experts
#define II 768    // intermediate
#define KTOP 8

typedef unsigned short u16;
typedef unsigned int u32;
typedef __bf16 bf16x8 __attribute__((ext_vector_type(8)));
typedef float f32x4 __attribute__((ext_vector_type(4)));

__device__ __forceinline__ u16 f2b(float f) {
    union { float f; unsigned int u; } v; v.f = f;
    unsigned int r = v.u + 0x7fffu + ((v.u >> 16) & 1u);  // RNE
    return (u16)(r >> 16);
}

// async 16B global -> LDS (dest must be wave-uniform base + lane*16)
__device__ __forceinline__ void gl2lds16(const u16* g, u16* l) {
    __builtin_amdgcn_global_load_lds(
        (const __attribute__((address_space(1))) u32*)g,
        (__attribute__((address_space(3))) u32*)l, 16, 0, 0);
}

// generic fp32 -> bf16 cast, 8 elems/thread
__global__ __launch_bounds__(256) void cast_kernel(const float* __restrict__ in,
                                                   u16* __restrict__ out) {
    const size_t i = ((size_t)blockIdx.x * 256 + threadIdx.x) * 8;
    const float4* s = reinterpret_cast<const float4*>(in + i);
    float4 a = s[0], b = s[1];
    union { u16 s[8]; uint4 v; } o;
    o.s[0] = f2b(a.x); o.s[1] = f2b(a.y); o.s[2] = f2b(a.z); o.s[3] = f2b(a.w);
    o.s[4] = f2b(b.x); o.s[5] = f2b(b.y); o.s[6] = f2b(b.z); o.s[7] = f2b(b.w);
    *reinterpret_cast<uint4*>(out + i) = o.v;
}

// one wave per token: logits -> softmax -> top8 -> renorm -> append to expert lists
__global__ void router_kernel(const float* __restrict__ hs, const float* __restrict__ gw,
                              int* __restrict__ counts, int* __restrict__ tok_id,
                              float* __restrict__ tok_w) {
    const int t = blockIdx.x;
    const int lane = threadIdx.x;
    float x[32];
#pragma unroll
    for (int j = 0; j < 32; j++) x[j] = hs[(size_t)t * HH + lane + 64 * j];
    __shared__ float logits[EE];
    for (int e = 0; e < EE; e++) {
        const float* w = gw + (size_t)e * HH;
        float acc = 0.f;
#pragma unroll
        for (int j = 0; j < 32; j++) acc += x[j] * w[lane + 64 * j];
#pragma unroll
        for (int off = 32; off > 0; off >>= 1) acc += __shfl_down(acc, off);
        if (lane == 0) logits[e] = acc;
    }
    __syncthreads();
    if (lane == 0) {
        float mx = logits[0];
        for (int e = 1; e < EE; e++) mx = fmaxf(mx, logits[e]);
        float p[EE];
        for (int e = 0; e < EE; e++) p[e] = expf(logits[e] - mx);
        int sel[KTOP]; float sw[KTOP]; float ssum = 0.f;
        for (int k = 0; k < KTOP; k++) {
            float best = -1.f; int bi = 0;
            for (int e = 0; e < EE; e++) { if (p[e] > best) { best = p[e]; bi = e; } }
            sel[k] = bi; sw[k] = best; ssum += best; p[bi] = -2.f;  // mark used
        }
        const float inv = 1.f / ssum;
        for (int k = 0; k < KTOP; k++) {
            const int e = sel[k];
            const int slot = atomicAdd(&counts[e], 1);
            tok_id[e * TT + slot] = t;
            tok_w[e * TT + slot] = sw[k] * inv;
        }
    }
}

__global__ void offsets_kernel(const int* __restrict__ counts, int* __restrict__ offsets) {
    if (threadIdx.x == 0 && blockIdx.x == 0) {
        int s = 0;
        for (int e = 0; e < EE; e++) { offsets[e] = s; s += counts[e]; }
        offsets[EE] = s;
    }
}

// grouped GEMM: [cnt x 2048] @ [64 x 2048]^T twice (gate+up), SiLU*up*w fused -> a_buf bf16
// v2: double-buffered LDS + prefetch-before-compute + single raw barrier per K-step
//     (no vmcnt(0) drain before compute; load latency hides under MFMA phase)
//     + bijective XCD-chunked block swizzle (1-D grid, nwg % 8 == 0).
__global__ __launch_bounds__(256) void gateup_kernel(
    const u16* __restrict__ hsb, const u16* __restrict__ wgb,
    const u16* __restrict__ wub, const int* __restrict__ counts,
    const int* __restrict__ offsets, const int* __restrict__ tok_id,
    const float* __restrict__ tok_w, u16* __restrict__ a_buf) {
    const int NWG = 16 * (II / 64) * EE;  // 6144, %8==0
    const int bid = blockIdx.x;
    const int w = (bid & 7) * (NWG >> 3) + (bid >> 3);  // XCD-chunked remap
    const int tt = w & 15;
    const int it = (w >> 4) % (II / 64);
    const int e  = w / (16 * (II / 64));
    const int cnt = counts[e];
    if (cnt == 0 || tt * 128 >= cnt) return;
    __shared__ u16 As[2][128 * 32];  // 16 KB per buf
    __shared__ u16 Bg[2][64 * 32];   // 4 KB per buf
    __shared__ u16 Bu[2][64 * 32];   // 4 KB per buf  -> 32 KB total, ~5 blocks/CU
    const int tid = threadIdx.x;
    const int wid = tid >> 6, lane = tid & 63;

    // staging: wave w covers rows [16w,16w+16); lane -> (row = 16w + l>>2, 16B chunk = l&3)
    const int srow = (wid << 4) + (lane >> 2);
    const int sc = (lane & 3) << 3;  // col offset in u16
    int aslot0 = tt * 128 + srow;      if (aslot0 >= cnt) aslot0 = cnt - 1;
    int aslot1 = tt * 128 + 64 + srow; if (aslot1 >= cnt) aslot1 = cnt - 1;
    const u16* ag0 = hsb + (size_t)tok_id[e * TT + aslot0] * HH + sc;
    const u16* ag1 = hsb + (size_t)tok_id[e * TT + aslot1] * HH + sc;
    const u16* bgs = wgb + ((size_t)e * II + it * 64 + srow) * HH + sc;
    const u16* bus = wub + ((size_t)e * II + it * 64 + srow) * HH + sc;
    const int aoff0 = srow * 32 + sc;          // base + lane*16B within wave segment
    const int aoff1 = (64 + srow) * 32 + sc;
    const int boff  = srow * 32 + sc;

    f32x4 accg[4][2], accu[4][2];
#pragma unroll
    for (int i = 0; i < 4; i++)
#pragma unroll
        for (int j = 0; j < 2; j++) {
            accg[i][j] = (f32x4){0.f, 0.f, 0.f, 0.f};
            accu[i][j] = (f32x4){0.f, 0.f, 0.f, 0.f};
        }

    const int wm = (wid & 1) * 64, wn = (wid >> 1) * 32;
    const int ml = lane & 15, q = lane >> 4;

#define STAGE_GU(B, K0)                          \
    do {                                         \
        gl2lds16(ag0 + (K0), &As[B][aoff0]);     \
        gl2lds16(ag1 + (K0), &As[B][aoff1]);     \
        gl2lds16(bgs + (K0), &Bg[B][boff]);      \
        gl2lds16(bus + (K0), &Bu[B][boff]);      \
    } while (0)

    // prologue: tile 0 into buf 0
    STAGE_GU(0, 0);
    asm volatile("s_waitcnt vmcnt(0)" ::: "memory");
    __builtin_amdgcn_s_barrier();

    const int NK = HH / 32;  // 64
    int cur = 0;
    for (int ki = 0; ki < NK; ++ki) {
        if (ki + 1 < NK) STAGE_GU(cur ^ 1, (ki + 1) * 32);  // prefetch next tile

        const u16* Ab  = As[cur];
        const u16* Bgb = Bg[cur];
        const u16* Bub = Bu[cur];
        bf16x8 af[4];
#pragma unroll
        for (int mi = 0; mi < 4; mi++)
            af[mi] = *reinterpret_cast<const bf16x8*>(Ab + (wm + mi * 16 + ml) * 32 + q * 8);
#pragma unroll
        for (int ni = 0; ni < 2; ni++) {
            bf16x8 bg = *reinterpret_cast<const bf16x8*>(Bgb + (wn + ni * 16 + ml) * 32 + q * 8);
            bf16x8 bu = *reinterpret_cast<const bf16x8*>(Bub + (wn + ni * 16 + ml) * 32 + q * 8);
#pragma unroll
            for (int mi = 0; mi < 4; mi++) {
                accg[mi][ni] = __builtin_amdgcn_mfma_f32_16x16x32_bf16(af[mi], bg, accg[mi][ni], 0, 0, 0);
                accu[mi][ni] = __builtin_amdgcn_mfma_f32_16x16x32_bf16(af[mi], bu, accu[mi][ni], 0, 0, 0);
            }
        }
        // next tile landed AND all waves done reading cur before it's overwritten
        asm volatile("s_waitcnt vmcnt(0)" ::: "memory");
        __builtin_amdgcn_s_barrier();
        cur ^= 1;
    }
#undef STAGE_GU

    const int obase = offsets[e];
#pragma unroll
    for (int mi = 0; mi < 4; mi++) {
#pragma unroll
        for (int reg = 0; reg < 4; reg++) {
            const int row = tt * 128 + wm + mi * 16 + q * 4 + reg;
            if (row < cnt) {
                const float w = tok_w[e * TT + row];
#pragma unroll
                for (int ni = 0; ni < 2; ni++) {
                    float g = accg[mi][ni][reg];
                    float u = accu[mi][ni][reg];
                    float a = (g / (1.f + expf(-g))) * u * w;  // silu(g)*u, routing weight folded in
                    a_buf[(size_t)(obase + row) * II + it * 64 + wn + ni * 16 + ml] = f2b(a);
                }
            }
        }
    }
}

// grouped GEMM: [cnt x 768] @ [128 x 768]^T -> atomicAdd scatter into out
// v2: same double-buffer + prefetch + single-barrier structure, XCD-chunked swizzle.
__global__ __launch_bounds__(256) void down_kernel(
    const u16* __restrict__ a_buf, const u16* __restrict__ wdb,
    const int* __restrict__ counts, const int* __restrict__ offsets,
    const int* __restrict__ tok_id, float* __restrict__ out) {
    const int NWG = 16 * (HH / 128) * EE;  // 8192, %8==0
    const int bid = blockIdx.x;
    const int w = (bid & 7) * (NWG >> 3) + (bid >> 3);
    const int tt = w & 15;
    const int ht = (w >> 4) % (HH / 128);
    const int e  = w / (16 * (HH / 128));
    const int cnt = counts[e];
    if (cnt == 0 || tt * 128 >= cnt) return;
    __shared__ u16 As[2][128 * 32];
    __shared__ u16 Bd[2][128 * 32];  // 32 KB total
    const int tid = threadIdx.x;
    const int wid = tid >> 6, lane = tid & 63;
    const int srow = (wid << 4) + (lane >> 2);
    const int sc = (lane & 3) << 3;
    int aslot0 = tt * 128 + srow;      if (aslot0 >= cnt) aslot0 = cnt - 1;
    int aslot1 = tt * 128 + 64 + srow; if (aslot1 >= cnt) aslot1 = cnt - 1;
    const u16* ag0 = a_buf + (size_t)(offsets[e] + aslot0) * II + sc;
    const u16* ag1 = a_buf + (size_t)(offsets[e] + aslot1) * II + sc;
    const u16* bs0 = wdb + ((size_t)e * HH + ht * 128 + srow) * II + sc;
    const u16* bs1 = wdb + ((size_t)e * HH + ht * 128 + 64 + srow) * II + sc;
    const int aoff0 = srow * 32 + sc;
    const int aoff1 = (64 + srow) * 32 + sc;

    f32x4 acc[4][4];
#pragma unroll
    for (int i = 0; i < 4; i++)
#pragma unroll
        for (int j = 0; j < 4; j++) acc[i][j] = (f32x4){0.f, 0.f, 0.f, 0.f};

    const int wm = (wid & 1) * 64, wn = (wid >> 1) * 64;
    const int ml = lane & 15, q = lane >> 4;

#define STAGE_DN(B, K0)                          \
    do {                                         \
        gl2lds16(ag0 + (K0), &As[B][aoff0]);     \
        gl2lds16(ag1 + (K0), &As[B][aoff1]);     \
        gl2lds16(bs0 + (K0), &Bd[B][aoff0]);     \
        gl2lds16(bs1 + (K0), &Bd[B][aoff1]);     \
    } while (0)

    STAGE_DN(0, 0);
    asm volatile("s_waitcnt vmcnt(0)" ::: "memory");
    __builtin_amdgcn_s_barrier();

    const int NK = II / 32;  // 24
    int cur = 0;
    for (int ki = 0; ki < NK; ++ki) {
        if (ki + 1 < NK) STAGE_DN(cur ^ 1, (ki + 1) * 32);

        const u16* Ab = As[cur];
        const u16* Bb = Bd[cur];
        bf16x8 af[4];
#pragma unroll
        for (int mi = 0; mi < 4; mi++)
            af[mi] = *reinterpret_cast<const bf16x8*>(Ab + (wm + mi * 16 + ml) * 32 + q * 8);
#pragma unroll
        for (int ni = 0; ni < 4; ni++) {
            bf16x8 bf = *reinterpret_cast<const bf16x8*>(Bb + (wn + ni * 16 + ml) * 32 + q * 8);
#pragma unroll
            for (int mi = 0; mi < 4; mi++)
                acc[mi][ni] = __builtin_amdgcn_mfma_f32_16x16x32_bf16(af[mi], bf, acc[mi][ni], 0, 0, 0);
        }
        asm volatile("s_waitcnt vmcnt(0)" ::: "memory");
        __builtin_amdgcn_s_barrier();
        cur ^= 1;
    }
#undef STAGE_DN

#pragma unroll
    for (int mi = 0; mi < 4; mi++) {
#pragma unroll
        for (int reg = 0; reg < 4; reg++) {
            const int row = tt * 128 + wm + mi * 16 + q * 4 + reg;
            if (row < cnt) {
                const int t = tok_id[e * TT + row];
                float* orow = out + (size_t)t * HH + ht * 128 + wn;
#pragma unroll
                for (int ni = 0; ni < 4; ni++)
                    atomicAdd(&orow[ni * 16 + ml], acc[mi][ni][reg]);
            }
        }
    }
}

extern "C" void kernel_launch(void* const* d_in, const int* in_sizes, int n_in,
                              void* d_out, int out_size, void* d_ws, size_t ws_size,
                              hipStream_t stream) {
    const float* hs     = (const float*)d_in[0];
    const float* gw     = (const float*)d_in[1];
    const float* w_gate = (const float*)d_in[2];
    const float* w_up   = (const float*)d_in[3];
    const float* w_down = (const float*)d_in[4];
    float* out = (float*)d_out;
    char* ws = (char*)d_ws;

    // workspace layout (~336 MB):
    int*   counts  = (int*)ws;                            // 32 ints
    int*   offsets = (int*)(ws + 256);                    // 33 ints
    int*   tok_id  = (int*)(ws + 1024);                   // 32*2048 ints  (256 KB)
    float* tok_w   = (float*)(ws + 1024 + EE * TT * 4);   // 32*2048 floats (256 KB)
    u16*   hsb     = (u16*)(ws + (1ull << 20));           // 2048*2048 bf16 (8 MB)
    u16*   a_buf   = (u16*)(ws + (16ull << 20));          // 16384*768 bf16 (25.2 MB)
    u16*   wgb     = (u16*)(ws + (48ull << 20));          // 32*768*2048 bf16 (96 MB)
    u16*   wub     = (u16*)(ws + (144ull << 20));         // 96 MB
    u16*   wdb     = (u16*)(ws + (240ull << 20));         // 96 MB

    hipMemsetAsync(out, 0, (size_t)TT * HH * sizeof(float), stream);
    hipMemsetAsync(counts, 0, EE * sizeof(int), stream);

    const int WELEM = EE * II * HH;  // 50,331,648
    cast_kernel<<<WELEM / (256 * 8), 256, 0, stream>>>(w_gate, wgb);
    cast_kernel<<<WELEM / (256 * 8), 256, 0, stream>>>(w_up, wub);
    cast_kernel<<<WELEM / (256 * 8), 256, 0, stream>>>(w_down, wdb);
    cast_kernel<<<(TT * HH) / (256 * 8), 256, 0, stream>>>(hs, hsb);

    router_kernel<<<TT, 64, 0, stream>>>(hs, gw, counts, tok_id, tok_w);
    offsets_kernel<<<1, 64, 0, stream>>>(counts, offsets);

    gateup_kernel<<<16 * (II / 64) * EE, 256, 0, stream>>>(
        hsb, wgb, wub, counts, offsets, tok_id, tok_w, a_buf);
    down_kernel<<<16 * (HH / 128) * EE, 256, 0, stream>>>(
        a_buf, wdb, counts, offsets, tok_id, out);
}